// Round 1
// baseline (185.709 us; speedup 1.0000x reference)
//
#include <hip/hip_runtime.h>
#include <stdint.h>
#include <stddef.h>

#define BB 4
#define NN 4096
#define DD 128

typedef _Float16 f16;
typedef _Float16 f16x8 __attribute__((ext_vector_type(8)));
typedef float f32x4 __attribute__((ext_vector_type(4)));

__device__ __forceinline__ void gl16(const f16* g, f16* l) {
  __builtin_amdgcn_global_load_lds(
      (const __attribute__((address_space(1))) unsigned int*)g,
      (__attribute__((address_space(3))) unsigned int*)l,
      16, 0, 0);
}

// ---- prep: f16 hi/lo split, numpy-exact row norms, input copies ----------
// 8 lanes per row replicate numpy pairwise_sum base case exactly:
// r[j] = sum_{i} a[8i+j] sequentially, then ((r0+r1)+(r2+r3))+((r4+r5)+(r6+r7))
__global__ __launch_bounds__(256) void prep_kernel(
    const float* __restrict__ x1, const float* __restrict__ x2,
    f16* __restrict__ x1h, f16* __restrict__ x1l,
    f16* __restrict__ x2h, f16* __restrict__ x2l,
    float* __restrict__ sq1, float* __restrict__ sq2,
    float* __restrict__ out)
{
  int gtid = blockIdx.x * blockDim.x + threadIdx.x;
  int gwave = gtid >> 6;
  int lane = gtid & 63;
  int sub = lane >> 3;   // 8 rows per wave
  int j = lane & 7;
  int row = gwave * 8 + sub;   // 0 .. 2*BB*NN-1
  const float* src; f16* dh; f16* dl; float* sq; float* cpy; int r;
  if (row < BB * NN) {
    r = row; src = x1; dh = x1h; dl = x1l; sq = sq1; cpy = out;
  } else {
    r = row - BB * NN; src = x2; dh = x2h; dl = x2l; sq = sq2;
    cpy = out + (size_t)BB * NN * DD;
  }
  const float* p = src + (size_t)r * DD;
  float acc = 0.0f;
  #pragma unroll
  for (int i = 0; i < DD / 8; ++i) {
    int c = j + i * 8;
    float v = p[c];
    float s = v * v;
    acc = (i == 0) ? s : (acc + s);
    f16 h = (f16)v;
    f16 l = (f16)(v - (float)h);
    dh[(size_t)r * DD + c] = h;
    dl[(size_t)r * DD + c] = l;
    cpy[(size_t)r * DD + c] = v;
  }
  acc = acc + __shfl_xor(acc, 1);
  acc = acc + __shfl_xor(acc, 2);
  acc = acc + __shfl_xor(acc, 4);
  if (j == 0) sq[r] = acc;
}

// ---- main: 128x128 tile, BK=32, split-f16 MFMA (3 mfma per frag pair),
//      fused dist epilogue + partial argmins ------------------------------
__global__ __launch_bounds__(256) void cdist_kernel(
    const f16* __restrict__ x2h, const f16* __restrict__ x2l,
    const f16* __restrict__ x1h, const f16* __restrict__ x1l,
    const float* __restrict__ sq2, const float* __restrict__ sq1,
    float* __restrict__ corr,
    float* __restrict__ p21v, int* __restrict__ p21i,
    float* __restrict__ p12v, int* __restrict__ p12i)
{
  __shared__ f16 Ah[128 * 32];
  __shared__ f16 Al[128 * 32];
  __shared__ f16 Bh[128 * 32];
  __shared__ f16 Bl[128 * 32];
  __shared__ float s2s[128];
  __shared__ float s1s[128];

  const int b = blockIdx.z;
  const int bn1 = blockIdx.x * 128;   // cols (x1 / N1)
  const int bn2 = blockIdx.y * 128;   // rows (x2 / N2)
  const int t = threadIdx.x;
  const int wid = t >> 6;
  const int lane = t & 63;
  const int wm = wid >> 1;   // wave row   (2 x 2 waves, 64x64 each)
  const int wn = wid & 1;    // wave col
  const int lr = lane & 15;
  const int lg = lane >> 4;

  const f16* gAh = x2h + (size_t)b * NN * DD;
  const f16* gAl = x2l + (size_t)b * NN * DD;
  const f16* gBh = x1h + (size_t)b * NN * DD;
  const f16* gBl = x1l + (size_t)b * NN * DD;

  if (t < 128) s2s[t] = sq2[(size_t)b * NN + bn2 + t];
  else         s1s[t - 128] = sq1[(size_t)b * NN + bn1 + (t - 128)];

  f32x4 acc[4][4];
  #pragma unroll
  for (int m = 0; m < 4; ++m)
    #pragma unroll
    for (int n = 0; n < 4; ++n)
      #pragma unroll
      for (int q = 0; q < 4; ++q) acc[m][n][q] = 0.0f;

  for (int k0 = 0; k0 < DD; k0 += 32) {
    // stage 4 tiles of [128][32] f16 via global_load_lds width=16
    {
      const int cb = wid * 128;   // 512 chunks of 16B per tile / 4 waves
      #pragma unroll
      for (int i = 0; i < 2; ++i) {
        const int c = cb + i * 64 + lane;
        const int rowc = c >> 2;
        const int koff = (c & 3) * 8;
        const int loff = (cb + i * 64) * 8;   // wave-uniform LDS base (f16 elems)
        const size_t ga = (size_t)(bn2 + rowc) * DD + k0 + koff;
        const size_t gb = (size_t)(bn1 + rowc) * DD + k0 + koff;
        gl16(gAh + ga, &Ah[loff]);
        gl16(gAl + ga, &Al[loff]);
        gl16(gBh + gb, &Bh[loff]);
        gl16(gBl + gb, &Bl[loff]);
      }
    }
    __syncthreads();

    f16x8 fah[4], fal[4], fbh[4], fbl[4];
    #pragma unroll
    for (int m = 0; m < 4; ++m) {
      const int off = (wm * 64 + m * 16 + lr) * 32 + lg * 8;
      fah[m] = *(const f16x8*)&Ah[off];
      fal[m] = *(const f16x8*)&Al[off];
    }
    #pragma unroll
    for (int n = 0; n < 4; ++n) {
      const int off = (wn * 64 + n * 16 + lr) * 32 + lg * 8;
      fbh[n] = *(const f16x8*)&Bh[off];
      fbl[n] = *(const f16x8*)&Bl[off];
    }
    #pragma unroll
    for (int m = 0; m < 4; ++m)
      #pragma unroll
      for (int n = 0; n < 4; ++n) {
        acc[m][n] = __builtin_amdgcn_mfma_f32_16x16x32_f16(fah[m], fbh[n], acc[m][n], 0, 0, 0);
        acc[m][n] = __builtin_amdgcn_mfma_f32_16x16x32_f16(fah[m], fbl[n], acc[m][n], 0, 0, 0);
        acc[m][n] = __builtin_amdgcn_mfma_f32_16x16x32_f16(fal[m], fbh[n], acc[m][n], 0, 0, 0);
      }
    __syncthreads();
  }

  // ---- epilogue: dist + corr store + in-register argmin partials ----
  float bv21[4][4]; int bi21[4][4];   // per (m,q): min over this wave's cols
  float bv12[4];    int bi12[4];      // per n: min over this wave's rows
  #pragma unroll
  for (int m = 0; m < 4; ++m)
    #pragma unroll
    for (int q = 0; q < 4; ++q) { bv21[m][q] = 3.4e38f; bi21[m][q] = 0; }
  #pragma unroll
  for (int n = 0; n < 4; ++n) { bv12[n] = 3.4e38f; bi12[n] = 0; }

  float* cbase = corr + (size_t)b * NN * NN;
  #pragma unroll
  for (int m = 0; m < 4; ++m) {
    #pragma unroll
    for (int n = 0; n < 4; ++n) {
      #pragma unroll
      for (int q = 0; q < 4; ++q) {
        const int rl = wm * 64 + m * 16 + lg * 4 + q;  // C/D: row=(lane>>4)*4+reg
        const int cl = wn * 64 + n * 16 + lr;          //      col=lane&15
        const float inner = acc[m][n][q];
        const float sqv = (s2s[rl] + s1s[cl]) - 2.0f * inner;
        const float dist = sqrtf(fmaxf(sqv, 0.0f));
        cbase[(size_t)(bn2 + rl) * NN + (bn1 + cl)] = dist;
        // cols ascend with n; rows ascend with (m,q): strict < keeps first idx
        if (dist < bv21[m][q]) { bv21[m][q] = dist; bi21[m][q] = bn1 + cl; }
        if (dist < bv12[n])    { bv12[n] = dist;    bi12[n] = bn2 + rl; }
      }
    }
  }

  // reduce over the 16 lanes sharing a row (same lg, lr varies)
  #pragma unroll
  for (int m = 0; m < 4; ++m)
    #pragma unroll
    for (int q = 0; q < 4; ++q) {
      float v = bv21[m][q]; int idx = bi21[m][q];
      #pragma unroll
      for (int mask = 1; mask < 16; mask <<= 1) {
        float ov = __shfl_xor(v, mask);
        int oi = __shfl_xor(idx, mask);
        if (ov < v || (ov == v && oi < idx)) { v = ov; idx = oi; }
      }
      if (lr == 0) {
        const int rowg = bn2 + wm * 64 + m * 16 + lg * 4 + q;
        const size_t o = ((size_t)b * NN + rowg) * 64 + (blockIdx.x * 2 + wn);
        p21v[o] = v; p21i[o] = idx;
      }
    }
  // reduce over the 4 lanes sharing a col (same lr, lg varies)
  #pragma unroll
  for (int n = 0; n < 4; ++n) {
    float v = bv12[n]; int idx = bi12[n];
    #pragma unroll
    for (int mask = 16; mask < 64; mask <<= 1) {
      float ov = __shfl_xor(v, mask);
      int oi = __shfl_xor(idx, mask);
      if (ov < v || (ov == v && oi < idx)) { v = ov; idx = oi; }
    }
    if (lg == 0) {
      const int colg = bn1 + wn * 64 + n * 16 + lr;
      const size_t o = ((size_t)b * NN + colg) * 64 + (blockIdx.y * 2 + wm);
      p12v[o] = v; p12i[o] = idx;
    }
  }
}

// ---- final argmin over 64 partial chunks, one wave per output row -------
__global__ __launch_bounds__(256) void argmin_reduce_kernel(
    const float* __restrict__ p21v, const int* __restrict__ p21i,
    const float* __restrict__ p12v, const int* __restrict__ p12i,
    float* __restrict__ out_i12, float* __restrict__ out_i21)
{
  int gtid = blockIdx.x * blockDim.x + threadIdx.x;
  int gwave = gtid >> 6;
  int lane = gtid & 63;
  const float* pv; const int* pi; float* dst; int r;
  if (gwave < BB * NN) { r = gwave; pv = p21v; pi = p21i; dst = out_i21; }
  else { r = gwave - BB * NN; pv = p12v; pi = p12i; dst = out_i12; }
  float v = pv[(size_t)r * 64 + lane];
  int idx = pi[(size_t)r * 64 + lane];
  #pragma unroll
  for (int mask = 1; mask < 64; mask <<= 1) {
    float ov = __shfl_xor(v, mask);
    int oi = __shfl_xor(idx, mask);
    if (ov < v || (ov == v && oi < idx)) { v = ov; idx = oi; }
  }
  if (lane == 0) dst[r] = (float)idx;
}

extern "C" void kernel_launch(void* const* d_in, const int* in_sizes, int n_in,
                              void* d_out, int out_size, void* d_ws, size_t ws_size,
                              hipStream_t stream) {
  (void)in_sizes; (void)n_in; (void)out_size; (void)ws_size;
  const float* x1 = (const float*)d_in[0];
  const float* x2 = (const float*)d_in[1];
  float* out = (float*)d_out;
  char* ws = (char*)d_ws;
  const size_t nd = (size_t)BB * NN * DD;   // 2,097,152 elems

  f16* x1h = (f16*)(ws + 0 * nd * 2);
  f16* x1l = (f16*)(ws + 1 * nd * 2);
  f16* x2h = (f16*)(ws + 2 * nd * 2);
  f16* x2l = (f16*)(ws + 3 * nd * 2);
  float* sq1 = (float*)(ws + 4 * nd * 2);
  float* sq2 = (float*)(ws + 4 * nd * 2 + (size_t)BB * NN * 4);
  char* pbase = ws + 4 * nd * 2 + 2 * (size_t)BB * NN * 4;
  float* p21v = (float*)(pbase + 0 * (size_t)BB * NN * 64 * 4);
  int*   p21i = (int*)  (pbase + 1 * (size_t)BB * NN * 64 * 4);
  float* p12v = (float*)(pbase + 2 * (size_t)BB * NN * 64 * 4);
  int*   p12i = (int*)  (pbase + 3 * (size_t)BB * NN * 64 * 4);

  // 2*BB*NN rows, 8 rows/wave, 4 waves/block -> 1024 blocks
  hipLaunchKernelGGL(prep_kernel, dim3(1024), dim3(256), 0, stream,
                     x1, x2, x1h, x1l, x2h, x2l, sq1, sq2, out);

  float* corr = out + 2 * nd;
  hipLaunchKernelGGL(cdist_kernel, dim3(32, 32, 4), dim3(256), 0, stream,
                     x2h, x2l, x1h, x1l, sq2, sq1, corr, p21v, p21i, p12v, p12i);

  float* out_i12 = out + 2 * nd + (size_t)BB * NN * NN;
  float* out_i21 = out_i12 + (size_t)BB * NN;
  // 2*BB*NN rows, 1 wave each, 4 waves/block -> 8192 blocks
  hipLaunchKernelGGL(argmin_reduce_kernel, dim3(8192), dim3(256), 0, stream,
                     p21v, p21i, p12v, p12i, out_i12, out_i21);
}

// Round 2
// 179.837 us; speedup vs baseline: 1.0327x; 1.0327x over previous
//
#include <hip/hip_runtime.h>
#include <stdint.h>
#include <stddef.h>

#define BB 4
#define NN 4096
#define DD 128

typedef _Float16 f16;
typedef _Float16 f16x8 __attribute__((ext_vector_type(8)));
typedef float f32x4 __attribute__((ext_vector_type(4)));

__device__ __forceinline__ void gl16(const f16* g, f16* l) {
  __builtin_amdgcn_global_load_lds(
      (const __attribute__((address_space(1))) unsigned int*)g,
      (__attribute__((address_space(3))) unsigned int*)l,
      16, 0, 0);
}

// ---- prep: f16 hi/lo split, numpy-exact row norms, input copies ----------
__global__ __launch_bounds__(256) void prep_kernel(
    const float* __restrict__ x1, const float* __restrict__ x2,
    f16* __restrict__ x1h, f16* __restrict__ x1l,
    f16* __restrict__ x2h, f16* __restrict__ x2l,
    float* __restrict__ sq1, float* __restrict__ sq2,
    float* __restrict__ out)
{
  int gtid = blockIdx.x * blockDim.x + threadIdx.x;
  int gwave = gtid >> 6;
  int lane = gtid & 63;
  int sub = lane >> 3;
  int j = lane & 7;
  int row = gwave * 8 + sub;
  const float* src; f16* dh; f16* dl; float* sq; float* cpy; int r;
  if (row < BB * NN) {
    r = row; src = x1; dh = x1h; dl = x1l; sq = sq1; cpy = out;
  } else {
    r = row - BB * NN; src = x2; dh = x2h; dl = x2l; sq = sq2;
    cpy = out + (size_t)BB * NN * DD;
  }
  const float* p = src + (size_t)r * DD;
  float acc = 0.0f;
  #pragma unroll
  for (int i = 0; i < DD / 8; ++i) {
    int c = j + i * 8;
    float v = p[c];
    float s = v * v;
    acc = (i == 0) ? s : (acc + s);
    f16 h = (f16)v;
    f16 l = (f16)(v - (float)h);
    dh[(size_t)r * DD + c] = h;
    dl[(size_t)r * DD + c] = l;
    cpy[(size_t)r * DD + c] = v;
  }
  acc = acc + __shfl_xor(acc, 1);
  acc = acc + __shfl_xor(acc, 2);
  acc = acc + __shfl_xor(acc, 4);
  if (j == 0) sq[r] = acc;
}

// ---- main: 128x128 tile, BK=32, split-f16 (3 mfma/frag-pair), A=x1 B=x2,
//      swizzled LDS (conflict-free), stage/MFMA overlap, dwordx4 stores ----
__global__ __launch_bounds__(256) void cdist_kernel(
    const f16* __restrict__ x1h, const f16* __restrict__ x1l,
    const f16* __restrict__ x2h, const f16* __restrict__ x2l,
    const float* __restrict__ sq1, const float* __restrict__ sq2,
    float* __restrict__ corr,
    float* __restrict__ p21v, int* __restrict__ p21i,
    float* __restrict__ p12v, int* __restrict__ p12i)
{
  __shared__ f16 Ah[128 * 32];
  __shared__ f16 Al[128 * 32];
  __shared__ f16 Bh[128 * 32];
  __shared__ f16 Bl[128 * 32];
  __shared__ float s1s[128];
  __shared__ float s2s[128];

  const int b = blockIdx.z;
  const int bn1 = blockIdx.x * 128;   // x1 / corr-col tile
  const int bn2 = blockIdx.y * 128;   // x2 / corr-row tile
  const int t = threadIdx.x;
  const int wid = t >> 6;
  const int lane = t & 63;
  const int wm = wid >> 1;   // which 64-col (n1) half
  const int wn = wid & 1;    // which 64-row (n2) half
  const int lr = lane & 15;
  const int lg = lane >> 4;

  const f16* gAh = x1h + (size_t)b * NN * DD;   // A = x1 (rows -> corr cols)
  const f16* gAl = x1l + (size_t)b * NN * DD;
  const f16* gBh = x2h + (size_t)b * NN * DD;   // B = x2 (rows -> corr rows)
  const f16* gBl = x2l + (size_t)b * NN * DD;

  if (t < 128) s1s[t] = sq1[(size_t)b * NN + bn1 + t];
  else         s2s[t - 128] = sq2[(size_t)b * NN + bn2 + (t - 128)];

  // staging geometry (swizzled global source, linear LDS dest)
  int goff_[2], loff_[2];
  #pragma unroll
  for (int i = 0; i < 2; ++i) {
    const int c = wid * 128 + i * 64 + lane;
    const int rowc = c >> 2;
    const int kc = (c & 3) ^ (rowc & 3) ^ ((rowc >> 2) & 3);
    goff_[i] = rowc * DD + kc * 8;          // f16 elements (k0 added later)
    loff_[i] = (wid * 128 + i * 64) * 8;    // wave-uniform LDS base
  }
#define STAGE(k0) do { \
    _Pragma("unroll") \
    for (int i = 0; i < 2; ++i) { \
      gl16(gAh + (bn1 * DD + goff_[i] + (k0)), &Ah[loff_[i]]); \
      gl16(gAl + (bn1 * DD + goff_[i] + (k0)), &Al[loff_[i]]); \
      gl16(gBh + (bn2 * DD + goff_[i] + (k0)), &Bh[loff_[i]]); \
      gl16(gBl + (bn2 * DD + goff_[i] + (k0)), &Bl[loff_[i]]); \
    } } while (0)

  f32x4 acc[4][4];
  #pragma unroll
  for (int m = 0; m < 4; ++m)
    #pragma unroll
    for (int n = 0; n < 4; ++n)
      #pragma unroll
      for (int q = 0; q < 4; ++q) acc[m][n][q] = 0.0f;

  STAGE(0);

  // swizzled read offset component (row&15 == lr for all frag rows)
  const int lgx8 = (lg ^ (lr & 3) ^ ((lr >> 2) & 3)) * 8;
  const int offA0 = (wm * 64 + lr) * 32 + lgx8;
  const int offB0 = (wn * 64 + lr) * 32 + lgx8;

  for (int it = 0; it < 4; ++it) {
    __syncthreads();    // vmcnt drain == wait for stage(it); barrier
    f16x8 fah[4], fal[4], fbh[4], fbl[4];
    #pragma unroll
    for (int m = 0; m < 4; ++m) {
      const int off = offA0 + m * (16 * 32);
      fah[m] = *(const f16x8*)&Ah[off];
      fal[m] = *(const f16x8*)&Al[off];
    }
    #pragma unroll
    for (int n = 0; n < 4; ++n) {
      const int off = offB0 + n * (16 * 32);
      fbh[n] = *(const f16x8*)&Bh[off];
      fbl[n] = *(const f16x8*)&Bl[off];
    }
    __syncthreads();    // all reads landed -> buffer free for next stage
    if (it < 3) STAGE((it + 1) * 32);   // gl_lds flies under the MFMAs below
    #pragma unroll
    for (int m = 0; m < 4; ++m)
      #pragma unroll
      for (int n = 0; n < 4; ++n) {
        acc[m][n] = __builtin_amdgcn_mfma_f32_16x16x32_f16(fah[m], fbh[n], acc[m][n], 0, 0, 0);
        acc[m][n] = __builtin_amdgcn_mfma_f32_16x16x32_f16(fah[m], fbl[n], acc[m][n], 0, 0, 0);
        acc[m][n] = __builtin_amdgcn_mfma_f32_16x16x32_f16(fal[m], fbh[n], acc[m][n], 0, 0, 0);
      }
  }
#undef STAGE

  // ---- epilogue ----
  // C/D layout with A=x1: corr-col (n1) = wm*64 + m*16 + lg*4 + q
  //                       corr-row (n2) = wn*64 + n*16 + lr
  float s2r[4];
  #pragma unroll
  for (int n = 0; n < 4; ++n) s2r[n] = s2s[wn * 64 + n * 16 + lr];
  float s1r[4][4];
  #pragma unroll
  for (int m = 0; m < 4; ++m)
    #pragma unroll
    for (int q = 0; q < 4; ++q) s1r[m][q] = s1s[wm * 64 + m * 16 + lg * 4 + q];

  float v21[4]; int i21[4];   // per n: min over n1 (this thread's 16 cols)
  #pragma unroll
  for (int n = 0; n < 4; ++n) { v21[n] = 3.4e38f; i21[n] = 0; }

  float* cbp = corr + (size_t)b * NN * NN;
  #pragma unroll
  for (int m = 0; m < 4; ++m) {
    const int n1b = wm * 64 + m * 16 + lg * 4;
    float v12[4]; int i12[4];   // per q (4 distinct cols): min over n2
    #pragma unroll
    for (int q = 0; q < 4; ++q) { v12[q] = 3.4e38f; i12[q] = 0; }
    #pragma unroll
    for (int n = 0; n < 4; ++n) {
      const int n2l = wn * 64 + n * 16 + lr;
      f32x4 dv;
      float sqc[4];
      #pragma unroll
      for (int q = 0; q < 4; ++q) {
        const float sv = fmaxf(fmaf(-2.0f, acc[m][n][q], s1r[m][q] + s2r[n]), 0.0f);
        sqc[q] = sv;
        dv[q] = sqrtf(sv);
      }
      *(f32x4*)(cbp + (size_t)(bn2 + n2l) * NN + (bn1 + n1b)) = dv;
      #pragma unroll
      for (int q = 0; q < 4; ++q) {
        // n1 ascends with (m,q): strict < keeps first index (np tie-break)
        if (sqc[q] < v21[n]) { v21[n] = sqc[q]; i21[n] = bn1 + n1b + q; }
        // n2 ascends with n: strict < keeps first index within thread
        if (sqc[q] < v12[q]) { v12[q] = sqc[q]; i12[q] = bn2 + n2l; }
      }
    }
    // reduce v12 over the 16 lanes (lr) sharing each col
    #pragma unroll
    for (int q = 0; q < 4; ++q) {
      float v = v12[q]; int idx = i12[q];
      #pragma unroll
      for (int mask = 1; mask < 16; mask <<= 1) {
        float ov = __shfl_xor(v, mask);
        int oi = __shfl_xor(idx, mask);
        if (ov < v || (ov == v && oi < idx)) { v = ov; idx = oi; }
      }
      if (lr == 0) {
        const int colg = bn1 + n1b + q;
        const size_t o = ((size_t)b * NN + colg) * 64 + (blockIdx.y * 2 + wn);
        p12v[o] = v; p12i[o] = idx;
      }
    }
  }
  // reduce v21 over the 4 lanes (lg) sharing each row
  #pragma unroll
  for (int n = 0; n < 4; ++n) {
    float v = v21[n]; int idx = i21[n];
    #pragma unroll
    for (int mask = 16; mask < 64; mask <<= 1) {
      float ov = __shfl_xor(v, mask);
      int oi = __shfl_xor(idx, mask);
      if (ov < v || (ov == v && oi < idx)) { v = ov; idx = oi; }
    }
    if (lg == 0) {
      const int rowg = bn2 + wn * 64 + n * 16 + lr;
      const size_t o = ((size_t)b * NN + rowg) * 64 + (blockIdx.x * 2 + wm);
      p21v[o] = v; p21i[o] = idx;
    }
  }
}

// ---- final argmin over 64 partial chunks, one wave per output row -------
__global__ __launch_bounds__(256) void argmin_reduce_kernel(
    const float* __restrict__ p21v, const int* __restrict__ p21i,
    const float* __restrict__ p12v, const int* __restrict__ p12i,
    float* __restrict__ out_i12, float* __restrict__ out_i21)
{
  int gtid = blockIdx.x * blockDim.x + threadIdx.x;
  int gwave = gtid >> 6;
  int lane = gtid & 63;
  const float* pv; const int* pi; float* dst; int r;
  if (gwave < BB * NN) { r = gwave; pv = p21v; pi = p21i; dst = out_i21; }
  else { r = gwave - BB * NN; pv = p12v; pi = p12i; dst = out_i12; }
  float v = pv[(size_t)r * 64 + lane];
  int idx = pi[(size_t)r * 64 + lane];
  #pragma unroll
  for (int mask = 1; mask < 64; mask <<= 1) {
    float ov = __shfl_xor(v, mask);
    int oi = __shfl_xor(idx, mask);
    if (ov < v || (ov == v && oi < idx)) { v = ov; idx = oi; }
  }
  if (lane == 0) dst[r] = (float)idx;
}

extern "C" void kernel_launch(void* const* d_in, const int* in_sizes, int n_in,
                              void* d_out, int out_size, void* d_ws, size_t ws_size,
                              hipStream_t stream) {
  (void)in_sizes; (void)n_in; (void)out_size; (void)ws_size;
  const float* x1 = (const float*)d_in[0];
  const float* x2 = (const float*)d_in[1];
  float* out = (float*)d_out;
  char* ws = (char*)d_ws;
  const size_t nd = (size_t)BB * NN * DD;

  f16* x1h = (f16*)(ws + 0 * nd * 2);
  f16* x1l = (f16*)(ws + 1 * nd * 2);
  f16* x2h = (f16*)(ws + 2 * nd * 2);
  f16* x2l = (f16*)(ws + 3 * nd * 2);
  float* sq1 = (float*)(ws + 4 * nd * 2);
  float* sq2 = (float*)(ws + 4 * nd * 2 + (size_t)BB * NN * 4);
  char* pbase = ws + 4 * nd * 2 + 2 * (size_t)BB * NN * 4;
  float* p21v = (float*)(pbase + 0 * (size_t)BB * NN * 64 * 4);
  int*   p21i = (int*)  (pbase + 1 * (size_t)BB * NN * 64 * 4);
  float* p12v = (float*)(pbase + 2 * (size_t)BB * NN * 64 * 4);
  int*   p12i = (int*)  (pbase + 3 * (size_t)BB * NN * 64 * 4);

  hipLaunchKernelGGL(prep_kernel, dim3(1024), dim3(256), 0, stream,
                     x1, x2, x1h, x1l, x2h, x2l, sq1, sq2, out);

  float* corr = out + 2 * nd;
  hipLaunchKernelGGL(cdist_kernel, dim3(32, 32, 4), dim3(256), 0, stream,
                     x1h, x1l, x2h, x2l, sq1, sq2, corr, p21v, p21i, p12v, p12i);

  float* out_i12 = out + 2 * nd + (size_t)BB * NN * NN;
  float* out_i21 = out_i12 + (size_t)BB * NN;
  hipLaunchKernelGGL(argmin_reduce_kernel, dim3(8192), dim3(256), 0, stream,
                     p21v, p21i, p12v, p12i, out_i12, out_i21);
}

// Round 3
// 152.209 us; speedup vs baseline: 1.2201x; 1.1815x over previous
//
#include <hip/hip_runtime.h>
#include <stdint.h>
#include <stddef.h>

#define BB 4
#define NN 4096
#define DD 128

typedef _Float16 f16;
typedef _Float16 f16x8 __attribute__((ext_vector_type(8)));
typedef float f32x4 __attribute__((ext_vector_type(4)));

__device__ __forceinline__ void gl16(const f16* g, f16* l) {
  __builtin_amdgcn_global_load_lds(
      (const __attribute__((address_space(1))) unsigned int*)g,
      (__attribute__((address_space(3))) unsigned int*)l,
      16, 0, 0);
}

__device__ __forceinline__ float fast_sqrt(float x) {
  float r;
  asm("v_sqrt_f32 %0, %1" : "=v"(r) : "v"(x));
  return r;
}

// ---- prep: f16 hi/lo split, numpy-exact row norms, input copies ----------
__global__ __launch_bounds__(256) void prep_kernel(
    const float* __restrict__ x1, const float* __restrict__ x2,
    f16* __restrict__ x1h, f16* __restrict__ x1l,
    f16* __restrict__ x2h, f16* __restrict__ x2l,
    float* __restrict__ sq1, float* __restrict__ sq2,
    float* __restrict__ out)
{
  int gtid = blockIdx.x * blockDim.x + threadIdx.x;
  int gwave = gtid >> 6;
  int lane = gtid & 63;
  int sub = lane >> 3;
  int j = lane & 7;
  int row = gwave * 8 + sub;
  const float* src; f16* dh; f16* dl; float* sq; float* cpy; int r;
  if (row < BB * NN) {
    r = row; src = x1; dh = x1h; dl = x1l; sq = sq1; cpy = out;
  } else {
    r = row - BB * NN; src = x2; dh = x2h; dl = x2l; sq = sq2;
    cpy = out + (size_t)BB * NN * DD;
  }
  const float* p = src + (size_t)r * DD;
  float acc = 0.0f;
  #pragma unroll
  for (int i = 0; i < DD / 8; ++i) {
    int c = j + i * 8;
    float v = p[c];
    float s = v * v;
    acc = (i == 0) ? s : (acc + s);
    f16 h = (f16)v;
    f16 l = (f16)(v - (float)h);
    dh[(size_t)r * DD + c] = h;
    dl[(size_t)r * DD + c] = l;
    cpy[(size_t)r * DD + c] = v;
  }
  acc = acc + __shfl_xor(acc, 1);
  acc = acc + __shfl_xor(acc, 2);
  acc = acc + __shfl_xor(acc, 4);
  if (j == 0) sq[r] = acc;
}

// ---- main: 128x128 tile, 8 waves (per-wave 64x32), BK=32, split-f16,
//      swizzled LDS, stage/MFMA overlap, NT dwordx4 stores, XCD swizzle ----
__global__ __launch_bounds__(512, 4) void cdist_kernel(
    const f16* __restrict__ x1h, const f16* __restrict__ x1l,
    const f16* __restrict__ x2h, const f16* __restrict__ x2l,
    const float* __restrict__ sq1, const float* __restrict__ sq2,
    float* __restrict__ corr,
    float* __restrict__ p21v, int* __restrict__ p21i,
    float* __restrict__ p12v, int* __restrict__ p12i)
{
  __shared__ f16 Ah[128 * 32];
  __shared__ f16 Al[128 * 32];
  __shared__ f16 Bh[128 * 32];
  __shared__ f16 Bl[128 * 32];
  __shared__ float s1s[128];
  __shared__ float s2s[128];

  const int b = blockIdx.z;
  // bijective XCD swizzle over the 1024 xy tiles (1024 % 8 == 0)
  int lin = blockIdx.y * 32 + blockIdx.x;
  lin = (lin & 7) * 128 + (lin >> 3);
  const int sbx = lin & 31;
  const int sby = lin >> 5;
  const int bn1 = sbx * 128;   // x1 / corr-col tile
  const int bn2 = sby * 128;   // x2 / corr-row tile

  const int t = threadIdx.x;
  const int wid = t >> 6;
  const int lane = t & 63;
  const int wm = wid & 1;    // n1 64-half
  const int wn = wid >> 1;   // n2 32-quarter (0..3)
  const int lr = lane & 15;
  const int lg = lane >> 4;

  const f16* gAh = x1h + (size_t)b * NN * DD;
  const f16* gAl = x1l + (size_t)b * NN * DD;
  const f16* gBh = x2h + (size_t)b * NN * DD;
  const f16* gBl = x2l + (size_t)b * NN * DD;

  if (t < 128) s1s[t] = sq1[(size_t)b * NN + bn1 + t];
  else if (t < 256) s2s[t - 128] = sq2[(size_t)b * NN + bn2 + (t - 128)];

  // staging geometry: 512 threads x 16B = one [128][32] f16 tile per array.
  // global source pre-swizzled, LDS dest linear (rule #21).
  const int rowc = t >> 2;
  const int kc = (t & 3) ^ (rowc & 3) ^ ((rowc >> 2) & 3);
  const int aoff = bn1 * DD + rowc * DD + kc * 8;
  const int boff = bn2 * DD + rowc * DD + kc * 8;
  const int loff = (wid * 64) * 8;   // wave-uniform LDS base (f16 elems)
#define STAGE(k0) do { \
    gl16(gAh + aoff + (k0), &Ah[loff]); \
    gl16(gAl + aoff + (k0), &Al[loff]); \
    gl16(gBh + boff + (k0), &Bh[loff]); \
    gl16(gBl + boff + (k0), &Bl[loff]); } while (0)

  f32x4 acc[4][2];
  #pragma unroll
  for (int m = 0; m < 4; ++m)
    #pragma unroll
    for (int n = 0; n < 2; ++n)
      #pragma unroll
      for (int q = 0; q < 4; ++q) acc[m][n][q] = 0.0f;

  STAGE(0);

  // swizzled read offset (row & 15 == lr for all fragment rows)
  const int lgx8 = (lg ^ (lr & 3) ^ ((lr >> 2) & 3)) * 8;
  const int offA0 = (wm * 64 + lr) * 32 + lgx8;
  const int offB0 = (wn * 32 + lr) * 32 + lgx8;

  for (int it = 0; it < 4; ++it) {
    __syncthreads();   // vmcnt drain == stage(it) landed
    f16x8 fah[4], fal[4], fbh[2], fbl[2];
    #pragma unroll
    for (int m = 0; m < 4; ++m) {
      fah[m] = *(const f16x8*)&Ah[offA0 + m * 512];
      fal[m] = *(const f16x8*)&Al[offA0 + m * 512];
    }
    #pragma unroll
    for (int n = 0; n < 2; ++n) {
      fbh[n] = *(const f16x8*)&Bh[offB0 + n * 512];
      fbl[n] = *(const f16x8*)&Bl[offB0 + n * 512];
    }
    __syncthreads();   // reads landed -> buffer free
    if (it < 3) STAGE((it + 1) * 32);   // flies under the MFMAs
    #pragma unroll
    for (int m = 0; m < 4; ++m)
      #pragma unroll
      for (int n = 0; n < 2; ++n) {
        acc[m][n] = __builtin_amdgcn_mfma_f32_16x16x32_f16(fah[m], fbh[n], acc[m][n], 0, 0, 0);
        acc[m][n] = __builtin_amdgcn_mfma_f32_16x16x32_f16(fah[m], fbl[n], acc[m][n], 0, 0, 0);
        acc[m][n] = __builtin_amdgcn_mfma_f32_16x16x32_f16(fal[m], fbh[n], acc[m][n], 0, 0, 0);
      }
  }
#undef STAGE

  // ---- epilogue ----
  // corr-col n1 = bn1 + wm*64 + m*16 + lg*4 + q ; corr-row n2 = bn2 + wn*32 + n*16 + lr
  float s2r[2];
  #pragma unroll
  for (int n = 0; n < 2; ++n) s2r[n] = s2s[wn * 32 + n * 16 + lr];
  float s1r[4][4];
  #pragma unroll
  for (int m = 0; m < 4; ++m)
    #pragma unroll
    for (int q = 0; q < 4; ++q) s1r[m][q] = s1s[wm * 64 + m * 16 + lg * 4 + q];

  float v21[2]; int i21[2];
  #pragma unroll
  for (int n = 0; n < 2; ++n) { v21[n] = 3.4e38f; i21[n] = 0; }

  float* cbp = corr + (size_t)b * NN * NN;
  #pragma unroll
  for (int m = 0; m < 4; ++m) {
    const int n1b = wm * 64 + m * 16 + lg * 4;
    float v12[4]; int i12[4];
    #pragma unroll
    for (int q = 0; q < 4; ++q) { v12[q] = 3.4e38f; i12[q] = 0; }
    #pragma unroll
    for (int n = 0; n < 2; ++n) {
      const int n2l = wn * 32 + n * 16 + lr;
      f32x4 dv;
      float sqc[4];
      #pragma unroll
      for (int q = 0; q < 4; ++q) {
        const float sv = fmaxf(fmaf(-2.0f, acc[m][n][q], s1r[m][q] + s2r[n]), 0.0f);
        sqc[q] = sv;
        dv[q] = fast_sqrt(sv);
      }
      __builtin_nontemporal_store(dv, (f32x4*)(cbp + (size_t)(bn2 + n2l) * NN + (bn1 + n1b)));
      #pragma unroll
      for (int q = 0; q < 4; ++q) {
        // n1 ascends with (m,q); n2 ascends with n: strict < = first-index tie-break
        if (sqc[q] < v21[n]) { v21[n] = sqc[q]; i21[n] = bn1 + n1b + q; }
        if (sqc[q] < v12[q]) { v12[q] = sqc[q]; i12[q] = bn2 + n2l; }
      }
    }
    // reduce v12 over the 16 lr-lanes (rows); lanes lg=0..3 hold distinct cols
    #pragma unroll
    for (int q = 0; q < 4; ++q) {
      float v = v12[q]; int idx = i12[q];
      #pragma unroll
      for (int mask = 1; mask < 16; mask <<= 1) {
        float ov = __shfl_xor(v, mask);
        int oi = __shfl_xor(idx, mask);
        if (ov < v || (ov == v && oi < idx)) { v = ov; idx = oi; }
      }
      if (lr == 0) {
        const int colg = bn1 + n1b + q;
        const size_t o = ((size_t)b * NN + colg) * 128 + (sby * 4 + wn);
        p12v[o] = v; p12i[o] = idx;
      }
    }
  }
  // reduce v21 over the 4 lg-lanes (cols); lanes lr=0..15 hold distinct rows
  #pragma unroll
  for (int n = 0; n < 2; ++n) {
    float v = v21[n]; int idx = i21[n];
    #pragma unroll
    for (int mask = 16; mask < 64; mask <<= 1) {
      float ov = __shfl_xor(v, mask);
      int oi = __shfl_xor(idx, mask);
      if (ov < v || (ov == v && oi < idx)) { v = ov; idx = oi; }
    }
    if (lg == 0) {
      const int rowg = bn2 + wn * 32 + n * 16 + lr;
      const size_t o = ((size_t)b * NN + rowg) * 64 + (sbx * 2 + wm);
      p21v[o] = v; p21i[o] = idx;
    }
  }
}

// ---- final argmin: p21 rows have 64 partials, p12 rows have 128 ---------
__global__ __launch_bounds__(256) void argmin_reduce_kernel(
    const float* __restrict__ p21v, const int* __restrict__ p21i,
    const float* __restrict__ p12v, const int* __restrict__ p12i,
    float* __restrict__ out_i12, float* __restrict__ out_i21)
{
  int gtid = blockIdx.x * blockDim.x + threadIdx.x;
  int gwave = gtid >> 6;
  int lane = gtid & 63;
  float v; int idx; float* dst; int r;
  if (gwave < BB * NN) {
    r = gwave;
    v = p21v[(size_t)r * 64 + lane];
    idx = p21i[(size_t)r * 64 + lane];
    dst = out_i21;
  } else {
    r = gwave - BB * NN;
    v = p12v[(size_t)r * 128 + lane];
    idx = p12i[(size_t)r * 128 + lane];
    float v2 = p12v[(size_t)r * 128 + 64 + lane];
    int i2 = p12i[(size_t)r * 128 + 64 + lane];
    if (v2 < v || (v2 == v && i2 < idx)) { v = v2; idx = i2; }
    dst = out_i12;
  }
  #pragma unroll
  for (int mask = 1; mask < 64; mask <<= 1) {
    float ov = __shfl_xor(v, mask);
    int oi = __shfl_xor(idx, mask);
    if (ov < v || (ov == v && oi < idx)) { v = ov; idx = oi; }
  }
  if (lane == 0) dst[r] = (float)idx;
}

extern "C" void kernel_launch(void* const* d_in, const int* in_sizes, int n_in,
                              void* d_out, int out_size, void* d_ws, size_t ws_size,
                              hipStream_t stream) {
  (void)in_sizes; (void)n_in; (void)out_size; (void)ws_size;
  const float* x1 = (const float*)d_in[0];
  const float* x2 = (const float*)d_in[1];
  float* out = (float*)d_out;
  char* ws = (char*)d_ws;
  const size_t nd = (size_t)BB * NN * DD;
  const size_t bn = (size_t)BB * NN;

  f16* x1h = (f16*)(ws + 0 * nd * 2);
  f16* x1l = (f16*)(ws + 1 * nd * 2);
  f16* x2h = (f16*)(ws + 2 * nd * 2);
  f16* x2l = (f16*)(ws + 3 * nd * 2);
  float* sq1 = (float*)(ws + 4 * nd * 2);
  float* sq2 = (float*)(ws + 4 * nd * 2 + bn * 4);
  char* pbase = ws + 4 * nd * 2 + 2 * bn * 4;
  float* p21v = (float*)(pbase);
  int*   p21i = (int*)  (pbase + 1 * bn * 64 * 4);
  float* p12v = (float*)(pbase + 2 * bn * 64 * 4);
  int*   p12i = (int*)  (pbase + 2 * bn * 64 * 4 + bn * 128 * 4);

  hipLaunchKernelGGL(prep_kernel, dim3(1024), dim3(256), 0, stream,
                     x1, x2, x1h, x1l, x2h, x2l, sq1, sq2, out);

  float* corr = out + 2 * nd;
  hipLaunchKernelGGL(cdist_kernel, dim3(32, 32, 4), dim3(512), 0, stream,
                     x1h, x1l, x2h, x2l, sq1, sq2, corr, p21v, p21i, p12v, p12i);

  float* out_i12 = out + 2 * nd + bn * (size_t)NN;
  float* out_i21 = out_i12 + bn;
  hipLaunchKernelGGL(argmin_reduce_kernel, dim3(8192), dim3(256), 0, stream,
                     p21v, p21i, p12v, p12i, out_i12, out_i21);
}